// Round 10
// baseline (62.770 us; speedup 1.0000x reference)
//
#include <hip/hip_runtime.h>

// inputs (B=64, N=128, N=128, L=16) f32; w (L,6,F=32) [l*192 + op*32 + f]; bias/diag_bias (F,)
#define NN 128
#define LL 16
#define FF 32

typedef float vf4 __attribute__((ext_vector_type(4)));

__global__ __launch_bounds__(256) void k_rowsum(const float* __restrict__ in,
                                                float* __restrict__ rs) {
    // one wave per (b,i) row: 2048 contiguous floats = 512 float4
    const int wave = threadIdx.x >> 6;
    const int lane = threadIdx.x & 63;
    const int row  = blockIdx.x * 4 + wave;   // b*NN + i, 8192 total
    const float4* src = reinterpret_cast<const float4*>(in) + (size_t)row * 512;
    float ax = 0.f, ay = 0.f, az = 0.f, aw = 0.f;
#pragma unroll
    for (int k = 0; k < 8; ++k) {
        float4 v = src[lane + 64 * k];
        ax += v.x; ay += v.y; az += v.z; aw += v.w;
    }
#pragma unroll
    for (int s = 4; s < 64; s <<= 1) {
        ax += __shfl_xor(ax, s);
        ay += __shfl_xor(ay, s);
        az += __shfl_xor(az, s);
        aw += __shfl_xor(aw, s);
    }
    if (lane < 4) {
        float4 o; o.x = ax; o.y = ay; o.z = az; o.w = aw;
        reinterpret_cast<float4*>(rs + (size_t)row * LL)[lane] = o;  // RAW rowsums
    }
}

__global__ __launch_bounds__(256) void k_prep(const float* __restrict__ rs_raw,
                                              const float* __restrict__ w,
                                              const float* __restrict__ bias,
                                              const float* __restrict__ dbias,
                                              float* __restrict__ gA,
                                              float* __restrict__ gC,
                                              float* __restrict__ gD) {
    // grid 256: blk -> (b = blk>>2, i-quarter = blk&3)
    __shared__ __align__(16) float sRS[NN * LL];     // 2048 floats
    __shared__ __align__(16) float sW[LL * 6 * FF];  // 3072 floats
    __shared__ float sTSp[8][16];
    __shared__ float sTS[16];
    const int blk = blockIdx.x;
    const int b   = blk >> 2;
    const int iq  = blk & 3;
    const int t   = threadIdx.x;

    const float4* rsrc = reinterpret_cast<const float4*>(rs_raw + (size_t)b * (NN * LL));
    reinterpret_cast<float4*>(sRS)[t]       = rsrc[t];
    reinterpret_cast<float4*>(sRS)[t + 256] = rsrc[t + 256];
    const float4* wsrc = reinterpret_cast<const float4*>(w);
    reinterpret_cast<float4*>(sW)[t]       = wsrc[t];
    reinterpret_cast<float4*>(sW)[t + 256] = wsrc[t + 256];
    reinterpret_cast<float4*>(sW)[t + 512] = wsrc[t + 512];
    __syncthreads();

    if (t < 128) {
        const int l = t & 15, c = t >> 4;
        float s = 0.f;
        for (int ii = 0; ii < 16; ++ii) s += sRS[(c * 16 + ii) * LL + l];
        sTSp[c][l] = s;
    }
    __syncthreads();
    if (t < 16) {
        float s = 0.f;
#pragma unroll
        for (int c = 0; c < 8; ++c) s += sTSp[c][t];
        sTS[t] = s;  // totsum raw
    }
    __syncthreads();

    const float invN  = 1.f / 50.f;
    const float invN2 = 1.f / 2500.f;
    for (int task = t; task < 1024; task += 256) {
        const int il = task >> 5, f = task & 31;
        const int i  = iq * 32 + il;
        float dA = 0.f, dC = 0.f, dD = 0.f, tA = 0.f, tD = 0.f;
#pragma unroll
        for (int l = 0; l < LL; ++l) {
            const float r  = sRS[i * LL + l];
            const float ts = sTS[l];
            dA += r  * sW[l * 192 + 2 * 32 + f];
            dC += r  * sW[l * 192 + 3 * 32 + f];
            dD += r  * sW[l * 192 + 4 * 32 + f];
            tA += ts * sW[l * 192 + 1 * 32 + f];
            tD += ts * sW[l * 192 + 5 * 32 + f];
        }
        const size_t o = ((size_t)b * NN + i) * FF + f;
        gA[o] = dA * invN + tA * invN2 + bias[f];
        gC[o] = dC * invN;
        gD[o] = dD * invN + tD * invN2 + dbias[f];
    }
}

// Pure-streaming main: no LDS, no barriers. One block per (b,i) row.
// t = p*8 + g8: g8 = f-quad, p = pixel lane; 8 lanes share each 16B input
// segment (hardware broadcast-coalesced). 4 independent j-iterations/thread.
__global__ __launch_bounds__(256) void k_main(const float* __restrict__ in,
                                              const float* __restrict__ w,
                                              const float* __restrict__ gA,
                                              const float* __restrict__ gC,
                                              const float* __restrict__ gD,
                                              float* __restrict__ out) {
    const int row = blockIdx.x;      // b*NN + i
    const int b   = row >> 7;
    const int i   = row & 127;
    const int t   = threadIdx.x;
    const int g8  = t & 7;
    const int p   = t >> 3;

    // hoisted per-block invariants (broadcast loads)
    float4 w0r[LL];
#pragma unroll
    for (int l = 0; l < LL; ++l)
        w0r[l] = *reinterpret_cast<const float4*>(w + l * 192 + g8 * 4);
    const float4 A4 = reinterpret_cast<const float4*>(gA + (size_t)row * FF)[g8];
    const float4 D4 = reinterpret_cast<const float4*>(gD + (size_t)row * FF)[g8];

    const vf4* rowbase = reinterpret_cast<const vf4*>(in) + (size_t)row * 512;
    float* outrow = out + (size_t)row * (NN * FF);

#pragma unroll
    for (int it = 0; it < 4; ++it) {
        const int j = p + 32 * it;
        const float4 C4 = reinterpret_cast<const float4*>(gC + ((size_t)b * NN + j) * FF)[g8];
        vf4 d0 = rowbase[j * 4 + 0];
        vf4 d1 = rowbase[j * 4 + 1];
        vf4 d2 = rowbase[j * 4 + 2];
        vf4 d3 = rowbase[j * 4 + 3];

        float a0 = A4.x + C4.x;
        float a1 = A4.y + C4.y;
        float a2 = A4.z + C4.z;
        float a3 = A4.w + C4.w;
        if (j == i) { a0 += D4.x; a1 += D4.y; a2 += D4.z; a3 += D4.w; }

        float in_l[LL];
        in_l[0]  = d0.x; in_l[1]  = d0.y; in_l[2]  = d0.z; in_l[3]  = d0.w;
        in_l[4]  = d1.x; in_l[5]  = d1.y; in_l[6]  = d1.z; in_l[7]  = d1.w;
        in_l[8]  = d2.x; in_l[9]  = d2.y; in_l[10] = d2.z; in_l[11] = d2.w;
        in_l[12] = d3.x; in_l[13] = d3.y; in_l[14] = d3.z; in_l[15] = d3.w;
#pragma unroll
        for (int l = 0; l < LL; ++l) {
            a0 = fmaf(in_l[l], w0r[l].x, a0);
            a1 = fmaf(in_l[l], w0r[l].y, a1);
            a2 = fmaf(in_l[l], w0r[l].z, a2);
            a3 = fmaf(in_l[l], w0r[l].w, a3);
        }
        vf4 o;
        o.x = fmaxf(a0, 0.f); o.y = fmaxf(a1, 0.f);
        o.z = fmaxf(a2, 0.f); o.w = fmaxf(a3, 0.f);
        __builtin_nontemporal_store(
            o, reinterpret_cast<vf4*>(outrow + j * FF + g8 * 4));
    }
}

extern "C" void kernel_launch(void* const* d_in, const int* in_sizes, int n_in,
                              void* d_out, int out_size, void* d_ws, size_t ws_size,
                              hipStream_t stream) {
    const float* in    = (const float*)d_in[0];  // (64,128,128,16)
    const float* w     = (const float*)d_in[1];  // (16,6,32)
    const float* bias  = (const float*)d_in[2];  // (32,)
    const float* dbias = (const float*)d_in[3];  // (32,)
    float* out = (float*)d_out;
    float* ws  = (float*)d_ws;

    float* rs = ws;            // 8192*16 = 131072 floats
    float* gA = ws + 131072;   // 262144 floats
    float* gC = ws + 393216;   // 262144 floats
    float* gD = ws + 655360;   // 262144 floats

    hipLaunchKernelGGL(k_rowsum, dim3(2048), dim3(256), 0, stream, in, rs);
    hipLaunchKernelGGL(k_prep,   dim3(256),  dim3(256), 0, stream, rs, w, bias, dbias, gA, gC, gD);
    hipLaunchKernelGGL(k_main,   dim3(8192), dim3(256), 0, stream, in, w, gA, gC, gD, out);
}

// Round 11
// 51.598 us; speedup vs baseline: 1.2165x; 1.2165x over previous
//
#include <hip/hip_runtime.h>

// inputs (B=64, N=128, N=128, L=16) f32; w (L,6,F=32) [l*192 + op*32 + f]; bias/diag_bias (F,)
#define NN 128
#define LL 16
#define FF 32

typedef float vf4 __attribute__((ext_vector_type(4)));

__global__ __launch_bounds__(256) void k_rowsum(const float* __restrict__ in,
                                                float* __restrict__ rs) {
    // one wave per (b,i) row: 2048 contiguous floats = 512 float4
    const int wave = threadIdx.x >> 6;
    const int lane = threadIdx.x & 63;
    const int row  = blockIdx.x * 4 + wave;   // b*NN + i, 8192 total (ascending order)
    const float4* src = reinterpret_cast<const float4*>(in) + (size_t)row * 512;
    float ax = 0.f, ay = 0.f, az = 0.f, aw = 0.f;
#pragma unroll
    for (int k = 0; k < 8; ++k) {
        float4 v = src[lane + 64 * k];
        ax += v.x; ay += v.y; az += v.z; aw += v.w;
    }
#pragma unroll
    for (int s = 4; s < 64; s <<= 1) {
        ax += __shfl_xor(ax, s);
        ay += __shfl_xor(ay, s);
        az += __shfl_xor(az, s);
        aw += __shfl_xor(aw, s);
    }
    if (lane < 4) {
        float4 o; o.x = ax; o.y = ay; o.z = az; o.w = aw;
        reinterpret_cast<float4*>(rs + (size_t)row * LL)[lane] = o;  // RAW rowsums
    }
}

// Fused main: REVERSED block order (LIFO vs k_rowsum's ascending traversal) so the
// input re-read hits L3: rows k_rowsum touched last are re-read first; nt output
// stores don't allocate, keeping the 64MB input resident in the 256MB L3.
__global__ __launch_bounds__(256) void k_fused(const float* __restrict__ in,
                                               const float* __restrict__ rs,
                                               const float* __restrict__ w,
                                               const float* __restrict__ bias,
                                               const float* __restrict__ dbias,
                                               float* __restrict__ out) {
    __shared__ __align__(16) float sIn[2][NN * 20];  // pixel stride 20 -> conflict-free b128
    __shared__ float sRS[NN][17];                    // stride 17 -> conflict-free scalar reads
    __shared__ float sTSp[8][16];
    __shared__ float sTS[16];
    __shared__ float sA[2][FF], sD[2][FF];
    const int blk = 4095 - (int)blockIdx.x;  // <-- LIFO reversal
    const int b   = blk >> 6;
    const int i0  = (blk & 63) * 2;
    const int t   = threadIdx.x;
    const int g   = t & 7;
    const int p   = t >> 3;
    const float invN  = 1.f / 50.f;
    const float invN2 = 1.f / 2500.f;

    const float4* rowbase =
        reinterpret_cast<const float4*>(in + ((size_t)b * NN + i0) * (NN * LL));
#pragma unroll
    for (int k = 0; k < 4; ++k) {
        const int v  = k * 256 + t;
        const int r  = v >> 9;
        const int vv = v & 511;
        const int j  = vv >> 2, lq = vv & 3;
        const float4 d = rowbase[v];
        *reinterpret_cast<float4*>(&sIn[r][j * 20 + lq * 4]) = d;
    }
    const float4* rsb = reinterpret_cast<const float4*>(rs + (size_t)b * NN * LL);
#pragma unroll
    for (int k = 0; k < 2; ++k) {
        const int v = k * 256 + t;
        const int row = v >> 2, lq = v & 3;
        const float4 d = rsb[v];
        sRS[row][lq * 4 + 0] = d.x; sRS[row][lq * 4 + 1] = d.y;
        sRS[row][lq * 4 + 2] = d.z; sRS[row][lq * 4 + 3] = d.w;
    }
    __syncthreads();

    if (t < 128) {
        const int l = t & 15, c = t >> 4;
        float s = 0.f;
#pragma unroll
        for (int ii = 0; ii < 16; ++ii) s += sRS[c * 16 + ii][l];
        sTSp[c][l] = s;
    }
    __syncthreads();
    if (t < 16) {
        float s = 0.f;
#pragma unroll
        for (int c = 0; c < 8; ++c) s += sTSp[c][t];
        sTS[t] = s;
    }
    __syncthreads();

    if (t < 64) {
        const int r = t >> 5, f = t & 31;
        const float* rrow = &sRS[i0 + r][0];
        float dA = 0.f, tA = 0.f, dD = 0.f, tD = 0.f;
#pragma unroll
        for (int l = 0; l < LL; ++l) {
            const float rv = rrow[l];
            const float ts = sTS[l];
            dA = fmaf(rv, w[l * 192 +  64 + f], dA);   // op2
            dD = fmaf(rv, w[l * 192 + 128 + f], dD);   // op4
            tA = fmaf(ts, w[l * 192 +  32 + f], tA);   // op1
            tD = fmaf(ts, w[l * 192 + 160 + f], tD);   // op5
        }
        sA[r][f] = dA * invN + tA * invN2 + bias[f];
        sD[r][f] = dD * invN + tD * invN2 + dbias[f];
    }

    float c4x[4] = {0.f, 0.f, 0.f, 0.f};
    float c4y[4] = {0.f, 0.f, 0.f, 0.f};
    float c4z[4] = {0.f, 0.f, 0.f, 0.f};
    float c4w[4] = {0.f, 0.f, 0.f, 0.f};
#pragma unroll
    for (int l = 0; l < LL; ++l) {
        const float4 wv4 = *reinterpret_cast<const float4*>(w + l * 192 + 96 + g * 4);
#pragma unroll
        for (int it = 0; it < 4; ++it) {
            const float rv = sRS[p + 32 * it][l];
            c4x[it] = fmaf(rv, wv4.x, c4x[it]);
            c4y[it] = fmaf(rv, wv4.y, c4y[it]);
            c4z[it] = fmaf(rv, wv4.z, c4z[it]);
            c4w[it] = fmaf(rv, wv4.w, c4w[it]);
        }
    }
#pragma unroll
    for (int it = 0; it < 4; ++it) {
        c4x[it] *= invN; c4y[it] *= invN; c4z[it] *= invN; c4w[it] *= invN;
    }

    float w0r[LL][4];
#pragma unroll
    for (int l = 0; l < LL; ++l) {
        const float4 wv4 = *reinterpret_cast<const float4*>(w + l * 192 + g * 4);
        w0r[l][0] = wv4.x; w0r[l][1] = wv4.y; w0r[l][2] = wv4.z; w0r[l][3] = wv4.w;
    }
    __syncthreads();

    float4 A4[2], D4[2];
#pragma unroll
    for (int r = 0; r < 2; ++r) {
        A4[r] = *reinterpret_cast<const float4*>(&sA[r][g * 4]);
        D4[r] = *reinterpret_cast<const float4*>(&sD[r][g * 4]);
    }

#pragma unroll
    for (int it = 0; it < 4; ++it) {
        const int j = p + 32 * it;
#pragma unroll
        for (int r = 0; r < 2; ++r) {
            float in_l[LL];
#pragma unroll
            for (int lq = 0; lq < 4; ++lq) {
                const float4 d = *reinterpret_cast<const float4*>(&sIn[r][j * 20 + lq * 4]);
                in_l[lq * 4 + 0] = d.x; in_l[lq * 4 + 1] = d.y;
                in_l[lq * 4 + 2] = d.z; in_l[lq * 4 + 3] = d.w;
            }
            float a0 = A4[r].x + c4x[it];
            float a1 = A4[r].y + c4y[it];
            float a2 = A4[r].z + c4z[it];
            float a3 = A4[r].w + c4w[it];
            if (j == i0 + r) { a0 += D4[r].x; a1 += D4[r].y; a2 += D4[r].z; a3 += D4[r].w; }
#pragma unroll
            for (int l = 0; l < LL; ++l) {
                a0 = fmaf(in_l[l], w0r[l][0], a0);
                a1 = fmaf(in_l[l], w0r[l][1], a1);
                a2 = fmaf(in_l[l], w0r[l][2], a2);
                a3 = fmaf(in_l[l], w0r[l][3], a3);
            }
            vf4 o;
            o.x = fmaxf(a0, 0.f); o.y = fmaxf(a1, 0.f);
            o.z = fmaxf(a2, 0.f); o.w = fmaxf(a3, 0.f);
            float* dst = out + ((((size_t)b * NN + (i0 + r)) * NN + j) * FF) + g * 4;
            __builtin_nontemporal_store(o, reinterpret_cast<vf4*>(dst));  // no-allocate
        }
    }
}

extern "C" void kernel_launch(void* const* d_in, const int* in_sizes, int n_in,
                              void* d_out, int out_size, void* d_ws, size_t ws_size,
                              hipStream_t stream) {
    const float* in    = (const float*)d_in[0];  // (64,128,128,16)
    const float* w     = (const float*)d_in[1];  // (16,6,32)
    const float* bias  = (const float*)d_in[2];  // (32,)
    const float* dbias = (const float*)d_in[3];  // (32,)
    float* out = (float*)d_out;
    float* rs  = (float*)d_ws;   // 8192*16 = 131072 floats (0.5 MiB raw rowsums)

    hipLaunchKernelGGL(k_rowsum, dim3(2048), dim3(256), 0, stream, in, rs);
    hipLaunchKernelGGL(k_fused,  dim3(4096), dim3(256), 0, stream,
                       in, rs, w, bias, dbias, out);
}